// Round 7
// baseline (537.093 us; speedup 1.0000x reference)
//
#include <hip/hip_runtime.h>
#include <hip/hip_bf16.h>

#define EDGE_DIM 64
#define UPD 256

typedef __attribute__((ext_vector_type(8))) short bf16x8;
typedef __attribute__((ext_vector_type(4))) float f32x4;

__device__ __forceinline__ short f2bf(float v) {
    __hip_bfloat16 b = __float2bfloat16(v);
    return *(short*)&b;
}
__device__ __forceinline__ float bf2f(short s) {
    __hip_bfloat16 b = *(__hip_bfloat16*)&s;
    return __bfloat162float(b);
}

// ---------------------------------------------------------------------------
// Per-block idx-dtype detection (deterministic across blocks).
// ---------------------------------------------------------------------------
__device__ __forceinline__ int detect_use64_block(const void* idx_v,
                                                  int n_edge, int nn,
                                                  int* bad_s) {
    if (threadIdx.x == 0) *bad_s = 0;
    __syncthreads();
    const long long* p = (const long long*)idx_v;
    int i = threadIdx.x;
    if (i < 256 && i < n_edge) {
        long long v = p[i];
        if (v < 0 || v >= (long long)nn) *bad_s = 1;  // benign race
    }
    __syncthreads();
    return !(*bad_s);
}

// ---------------------------------------------------------------------------
// Counting sort phase A: per-node histogram.
// ---------------------------------------------------------------------------
__global__ __launch_bounds__(256) void count_kernel(
    const void* __restrict__ idx_v, int n_edge, int nn,
    int* __restrict__ count) {
    __shared__ int bad_s;
    const int use64 = detect_use64_block(idx_v, n_edge, nn, &bad_s);
    const long long* i64 = (const long long*)idx_v;
    const int* i32 = (const int*)idx_v;
    for (int e = blockIdx.x * blockDim.x + threadIdx.x; e < n_edge;
         e += gridDim.x * blockDim.x) {
        int n = use64 ? (int)i64[e] : i32[e];
        atomicAdd(&count[n], 1);
    }
}

// ---------------------------------------------------------------------------
// Exclusive scan over count[nn] -> base[nn+1]  (3 kernels).
// ---------------------------------------------------------------------------
__global__ __launch_bounds__(256) void scan_a(const int* __restrict__ count,
                                              int* __restrict__ base,
                                              int* __restrict__ partial,
                                              int nn) {
    __shared__ int s[256];
    const int tid = threadIdx.x;
    const int i0 = blockIdx.x * 1024 + tid * 4;
    int c[4], tsum = 0;
#pragma unroll
    for (int j = 0; j < 4; ++j) {
        c[j] = (i0 + j < nn) ? count[i0 + j] : 0;
        tsum += c[j];
    }
    s[tid] = tsum;
    __syncthreads();
    for (int off = 1; off < 256; off <<= 1) {
        int v = (tid >= off) ? s[tid - off] : 0;
        __syncthreads();
        s[tid] += v;
        __syncthreads();
    }
    int run = s[tid] - tsum;
    if (tid == 255) partial[blockIdx.x] = s[255];
#pragma unroll
    for (int j = 0; j < 4; ++j) {
        if (i0 + j < nn) base[i0 + j] = run;
        run += c[j];
    }
}

__global__ __launch_bounds__(256) void scan_b(int* __restrict__ partial,
                                              int nblk) {
    __shared__ int s[256];
    const int tid = threadIdx.x;
    int v = (tid < nblk) ? partial[tid] : 0;
    s[tid] = v;
    __syncthreads();
    for (int off = 1; off < 256; off <<= 1) {
        int u = (tid >= off) ? s[tid - off] : 0;
        __syncthreads();
        s[tid] += u;
        __syncthreads();
    }
    if (tid < nblk) partial[tid] = s[tid] - v;
}

__global__ __launch_bounds__(256) void scan_c(int* __restrict__ base,
                                              int* __restrict__ cursor,
                                              const int* __restrict__ partial,
                                              int nn, int n_edge) {
    const int tid = threadIdx.x;
    const int b = blockIdx.x;
    const int add = partial[b];
    const int i0 = b * 1024 + tid * 4;
#pragma unroll
    for (int j = 0; j < 4; ++j) {
        int i = i0 + j;
        if (i < nn) {
            int v = base[i] + add;
            base[i] = v;
            cursor[i] = v;
        }
    }
    if (b == 0 && tid == 0) base[nn] = n_edge;
}

// ---------------------------------------------------------------------------
// Phase B: slot[e] = destination position of edge e in node-sorted order.
// ---------------------------------------------------------------------------
__global__ __launch_bounds__(256) void fill_slot_kernel(
    const void* __restrict__ idx_v, int n_edge, int nn,
    int* __restrict__ cursor, int* __restrict__ slot) {
    __shared__ int bad_s;
    const int use64 = detect_use64_block(idx_v, n_edge, nn, &bad_s);
    const long long* i64 = (const long long*)idx_v;
    const int* i32 = (const int*)idx_v;
    for (int e = blockIdx.x * blockDim.x + threadIdx.x; e < n_edge;
         e += gridDim.x * blockDim.x) {
        int n = use64 ? (int)i64[e] : i32[e];
        slot[e] = atomicAdd(&cursor[n], 1);
    }
}

// ---------------------------------------------------------------------------
// Phase C: streaming gate + scatter-store (NO RMW, NO dependent addresses).
// Wave processes 4 edges per iteration in ORIGINAL order: x reads coalesced
// and affine, rbf via wave-uniform scalar loads (16 fmac w/ SGPR operand),
// y[slot[e]] written as one 256B (f32) or 128B (bf16) burst.
// ---------------------------------------------------------------------------
__global__ __launch_bounds__(256) void scatter_y_kernel(
    const float* __restrict__ x, const float* __restrict__ rbf,
    const int* __restrict__ slot, const float* __restrict__ Wrbf,
    float* __restrict__ yf, __hip_bfloat16* __restrict__ yb, int use_bf16,
    int n_edge) {
    const int lane = threadIdx.x & 63;
    float wreg[16];
#pragma unroll
    for (int q = 0; q < 16; ++q) wreg[q] = Wrbf[q * EDGE_DIM + lane];

    const int wid = __builtin_amdgcn_readfirstlane(threadIdx.x >> 6);
    const int gw = blockIdx.x * 4 + wid;
    const int nwaves = gridDim.x * 4;

    for (int e0 = gw * 4; e0 < n_edge; e0 += nwaves * 4) {
        if (e0 + 4 <= n_edge) {
            int s0 = __builtin_amdgcn_readfirstlane(slot[e0 + 0]);
            int s1 = __builtin_amdgcn_readfirstlane(slot[e0 + 1]);
            int s2 = __builtin_amdgcn_readfirstlane(slot[e0 + 2]);
            int s3 = __builtin_amdgcn_readfirstlane(slot[e0 + 3]);
            float xv0 = x[(size_t)(e0 + 0) * EDGE_DIM + lane];
            float xv1 = x[(size_t)(e0 + 1) * EDGE_DIM + lane];
            float xv2 = x[(size_t)(e0 + 2) * EDGE_DIM + lane];
            float xv3 = x[(size_t)(e0 + 3) * EDGE_DIM + lane];
            float g0 = 0.f, g1 = 0.f, g2 = 0.f, g3 = 0.f;
            const float* r0 = rbf + (size_t)(e0 + 0) * 16;
            const float* r1 = rbf + (size_t)(e0 + 1) * 16;
            const float* r2 = rbf + (size_t)(e0 + 2) * 16;
            const float* r3 = rbf + (size_t)(e0 + 3) * 16;
#pragma unroll
            for (int q = 0; q < 16; ++q) {
                g0 = fmaf(r0[q], wreg[q], g0);
                g1 = fmaf(r1[q], wreg[q], g1);
                g2 = fmaf(r2[q], wreg[q], g2);
                g3 = fmaf(r3[q], wreg[q], g3);
            }
            if (use_bf16) {
                yb[(size_t)s0 * EDGE_DIM + lane] = __float2bfloat16(g0 * xv0);
                yb[(size_t)s1 * EDGE_DIM + lane] = __float2bfloat16(g1 * xv1);
                yb[(size_t)s2 * EDGE_DIM + lane] = __float2bfloat16(g2 * xv2);
                yb[(size_t)s3 * EDGE_DIM + lane] = __float2bfloat16(g3 * xv3);
            } else {
                yf[(size_t)s0 * EDGE_DIM + lane] = g0 * xv0;
                yf[(size_t)s1 * EDGE_DIM + lane] = g1 * xv1;
                yf[(size_t)s2 * EDGE_DIM + lane] = g2 * xv2;
                yf[(size_t)s3 * EDGE_DIM + lane] = g3 * xv3;
            }
        } else {
            for (int e = e0; e < n_edge; ++e) {
                int sl = __builtin_amdgcn_readfirstlane(slot[e]);
                float xv = x[(size_t)e * EDGE_DIM + lane];
                const float* rp = rbf + (size_t)e * 16;
                float g = 0.f;
#pragma unroll
                for (int q = 0; q < 16; ++q) g = fmaf(rp[q], wreg[q], g);
                if (use_bf16)
                    yb[(size_t)sl * EDGE_DIM + lane] = __float2bfloat16(g * xv);
                else
                    yf[(size_t)sl * EDGE_DIM + lane] = g * xv;
            }
        }
    }
}

// ---------------------------------------------------------------------------
// Pack all 4 weight matrices into MFMA-fragment bf16 hi/lo order.
// ---------------------------------------------------------------------------
__device__ __forceinline__ void pack_body(const float* __restrict__ W,
                                          short* __restrict__ out, int t) {
    int l = t & 63, f = t >> 6;
    int kt = f >> 4, nt = f & 15;
    int kbase = kt * 32 + (l >> 4) * 8;
    int col = nt * 16 + (l & 15);
#pragma unroll
    for (int j = 0; j < 8; ++j) {
        float v = W[(kbase + j) * UPD + col];
        short hb = f2bf(v);
        short lb = f2bf(v - bf2f(hb));
        out[f * 1024 + l * 8 + j] = hb;
        out[f * 1024 + 512 + l * 8 + j] = lb;
    }
}

__global__ __launch_bounds__(256) void pack_all_kernel(
    const float* __restrict__ Wup, const float* __restrict__ W1,
    const float* __restrict__ W2, const float* __restrict__ W3,
    short* __restrict__ oup, short* __restrict__ o1, short* __restrict__ o2,
    short* __restrict__ o3) {
    const int b = blockIdx.x;
    if (b < 8) {
        pack_body(Wup, oup, b * 256 + threadIdx.x);
    } else if (b < 40) {
        pack_body(W1, o1, (b - 8) * 256 + threadIdx.x);
    } else if (b < 72) {
        pack_body(W2, o2, (b - 40) * 256 + threadIdx.x);
    } else {
        pack_body(W3, o3, (b - 72) * 256 + threadIdx.x);
    }
}

// ---------------------------------------------------------------------------
// MFMA node MLP with fused y-segment-sum staging.
// ---------------------------------------------------------------------------
template <int NK>
__device__ __forceinline__ void mm_layer(const short* AH, const short* AL,
                                         const short* __restrict__ Wpk,
                                         int lr, int lh, int lane, int wq,
                                         f32x4 acc[4][4]) {
#pragma unroll
    for (int kt = 0; kt < NK; ++kt) {
        bf16x8 a[4][2];
#pragma unroll
        for (int m = 0; m < 4; ++m) {
            int r = m * 16 + lr;
            int ch = (kt * 4 + lh) ^ (r & 7);
            int off = r * 256 + ch * 8;  // shorts
            a[m][0] = *(const bf16x8*)(AH + off);
            a[m][1] = *(const bf16x8*)(AL + off);
        }
        bf16x8 b[4][2];
#pragma unroll
        for (int nf = 0; nf < 4; ++nf) {
            int f = kt * 16 + wq * 4 + nf;
            const short* p = Wpk + f * 1024 + lane * 8;
            b[nf][0] = *(const bf16x8*)(p);
            b[nf][1] = *(const bf16x8*)(p + 512);
        }
#pragma unroll
        for (int m = 0; m < 4; ++m)
#pragma unroll
            for (int nf = 0; nf < 4; ++nf)
                acc[m][nf] = __builtin_amdgcn_mfma_f32_16x16x32_bf16(
                    a[m][0], b[nf][0], acc[m][nf], 0, 0, 0);
#pragma unroll
        for (int m = 0; m < 4; ++m)
#pragma unroll
            for (int nf = 0; nf < 4; ++nf)
                acc[m][nf] = __builtin_amdgcn_mfma_f32_16x16x32_bf16(
                    a[m][0], b[nf][1], acc[m][nf], 0, 0, 0);
#pragma unroll
        for (int m = 0; m < 4; ++m)
#pragma unroll
            for (int nf = 0; nf < 4; ++nf)
                acc[m][nf] = __builtin_amdgcn_mfma_f32_16x16x32_bf16(
                    a[m][1], b[nf][0], acc[m][nf], 0, 0, 0);
    }
}

template <bool ACT>
__device__ __forceinline__ void epilogue_store(f32x4 acc[4][4], short* AH,
                                               short* AL,
                                               const float* __restrict__ bias,
                                               int lr, int lh, int wq) {
    float bv[4] = {0.f, 0.f, 0.f, 0.f};
    if (bias) {
#pragma unroll
        for (int nf = 0; nf < 4; ++nf) bv[nf] = bias[wq * 64 + nf * 16 + lr];
    }
#pragma unroll
    for (int m = 0; m < 4; ++m)
#pragma unroll
        for (int nf = 0; nf < 4; ++nf) {
            int c = wq * 64 + nf * 16 + lr;
#pragma unroll
            for (int reg = 0; reg < 4; ++reg) {
                float v = acc[m][nf][reg] + bv[nf];
                if (ACT) v = v / (1.f + __expf(-v));
                int r = m * 16 + lh * 4 + reg;
                short hb = f2bf(v);
                short lb = f2bf(v - bf2f(hb));
                int off = r * 256 + (((c >> 3) ^ (r & 7)) * 8) + (c & 7);
                AH[off] = hb;
                AL[off] = lb;
            }
        }
}

__global__ __launch_bounds__(256, 2) void node_mlp_mfma2(
    const float* __restrict__ yf, const __hip_bfloat16* __restrict__ yb,
    int use_bf16, const int* __restrict__ base,
    const short* __restrict__ Wup_pk, const short* __restrict__ W1_pk,
    const short* __restrict__ W2_pk, const short* __restrict__ W3_pk,
    const float* __restrict__ b1, const float* __restrict__ b2,
    const float* __restrict__ b3, const float* __restrict__ W_out,
    float* __restrict__ out, int nn) {
    __shared__ short AH[64 * 256];
    __shared__ short AL[64 * 256];
    __shared__ float Bpart[64 * 4];

    const int tid = threadIdx.x;
    const int lane = tid & 63;
    const int wq = __builtin_amdgcn_readfirstlane(tid >> 6);
    const int lr = lane & 15, lh = lane >> 4;
    const int node0 = blockIdx.x * 64;

    // Fused staging: wave wq sums y rows for nodes [wq*16, wq*16+16),
    // writes bf16 hi/lo into swizzled LDS.
    for (int i = 0; i < 16; ++i) {
        const int r = wq * 16 + i;
        const int n = node0 + r;
        float acc = 0.f;
        if (n < nn) {
            const int b0 = __builtin_amdgcn_readfirstlane(base[n]);
            const int b1v = __builtin_amdgcn_readfirstlane(base[n + 1]);
            int s = b0;
            if (use_bf16) {
                float a0 = 0.f, a1 = 0.f, a2 = 0.f, a3 = 0.f;
                for (; s + 4 <= b1v; s += 4) {
                    a0 += bf2f(*(const short*)&yb[(size_t)(s + 0) * EDGE_DIM + lane]);
                    a1 += bf2f(*(const short*)&yb[(size_t)(s + 1) * EDGE_DIM + lane]);
                    a2 += bf2f(*(const short*)&yb[(size_t)(s + 2) * EDGE_DIM + lane]);
                    a3 += bf2f(*(const short*)&yb[(size_t)(s + 3) * EDGE_DIM + lane]);
                }
                acc = (a0 + a1) + (a2 + a3);
                for (; s < b1v; ++s)
                    acc += bf2f(*(const short*)&yb[(size_t)s * EDGE_DIM + lane]);
            } else {
                float a0 = 0.f, a1 = 0.f, a2 = 0.f, a3 = 0.f;
                for (; s + 4 <= b1v; s += 4) {
                    a0 += yf[(size_t)(s + 0) * EDGE_DIM + lane];
                    a1 += yf[(size_t)(s + 1) * EDGE_DIM + lane];
                    a2 += yf[(size_t)(s + 2) * EDGE_DIM + lane];
                    a3 += yf[(size_t)(s + 3) * EDGE_DIM + lane];
                }
                acc = (a0 + a1) + (a2 + a3);
                for (; s < b1v; ++s)
                    acc += yf[(size_t)s * EDGE_DIM + lane];
            }
        }
        short hb = f2bf(acc);
        short lb = f2bf(acc - bf2f(hb));
        int off = r * 256 + (((lane >> 3) ^ (r & 7)) * 8) + (lane & 7);
        AH[off] = hb;
        AL[off] = lb;
    }
    __syncthreads();

    f32x4 acc[4][4];

#pragma unroll
    for (int m = 0; m < 4; ++m)
#pragma unroll
        for (int n = 0; n < 4; ++n) acc[m][n] = (f32x4){0.f, 0.f, 0.f, 0.f};
    mm_layer<2>(AH, AL, Wup_pk, lr, lh, lane, wq, acc);
    __syncthreads();
    epilogue_store<false>(acc, AH, AL, nullptr, lr, lh, wq);
    __syncthreads();

#pragma unroll
    for (int m = 0; m < 4; ++m)
#pragma unroll
        for (int n = 0; n < 4; ++n) acc[m][n] = (f32x4){0.f, 0.f, 0.f, 0.f};
    mm_layer<8>(AH, AL, W1_pk, lr, lh, lane, wq, acc);
    __syncthreads();
    epilogue_store<true>(acc, AH, AL, b1, lr, lh, wq);
    __syncthreads();

#pragma unroll
    for (int m = 0; m < 4; ++m)
#pragma unroll
        for (int n = 0; n < 4; ++n) acc[m][n] = (f32x4){0.f, 0.f, 0.f, 0.f};
    mm_layer<8>(AH, AL, W2_pk, lr, lh, lane, wq, acc);
    __syncthreads();
    epilogue_store<true>(acc, AH, AL, b2, lr, lh, wq);
    __syncthreads();

#pragma unroll
    for (int m = 0; m < 4; ++m)
#pragma unroll
        for (int n = 0; n < 4; ++n) acc[m][n] = (f32x4){0.f, 0.f, 0.f, 0.f};
    mm_layer<8>(AH, AL, W3_pk, lr, lh, lane, wq, acc);

    float b3v[4], wo[4];
#pragma unroll
    for (int nf = 0; nf < 4; ++nf) {
        int c = wq * 64 + nf * 16 + lr;
        b3v[nf] = b3[c];
        wo[nf] = W_out[c];
    }
#pragma unroll
    for (int m = 0; m < 4; ++m) {
#pragma unroll
        for (int reg = 0; reg < 4; ++reg) {
            float s = 0.f;
#pragma unroll
            for (int nf = 0; nf < 4; ++nf) {
                float v = acc[m][nf][reg] + b3v[nf];
                v = v / (1.f + __expf(-v));
                s = fmaf(v, wo[nf], s);
            }
            s += __shfl_xor(s, 1);
            s += __shfl_xor(s, 2);
            s += __shfl_xor(s, 4);
            s += __shfl_xor(s, 8);
            if (lr == 0) Bpart[(m * 16 + lh * 4 + reg) * 4 + wq] = s;
        }
    }
    __syncthreads();
    if (tid < 64) {
        float s = Bpart[tid * 4] + Bpart[tid * 4 + 1] + Bpart[tid * 4 + 2] +
                  Bpart[tid * 4 + 3];
        if (node0 + tid < nn) out[node0 + tid] = s;
    }
}

// ---------------------------------------------------------------------------
extern "C" void kernel_launch(void* const* d_in, const int* in_sizes, int n_in,
                              void* d_out, int out_size, void* d_ws, size_t ws_size,
                              hipStream_t stream) {
    const float* x     = (const float*)d_in[0];
    const float* rbf   = (const float*)d_in[1];
    const void*  idx   = d_in[2];
    const float* W_rbf = (const float*)d_in[4];
    const float* W_up  = (const float*)d_in[5];
    const float* W1    = (const float*)d_in[6];
    const float* b1    = (const float*)d_in[7];
    const float* W2    = (const float*)d_in[8];
    const float* b2    = (const float*)d_in[9];
    const float* W3    = (const float*)d_in[10];
    const float* b3    = (const float*)d_in[11];
    const float* W_out = (const float*)d_in[12];
    float* out = (float*)d_out;

    const int n_edge = in_sizes[0] / EDGE_DIM;
    const int nn = out_size;

    // Workspace layout
    char* p = (char*)d_ws;
    short* wup_pk = (short*)p;  p += (size_t)32 * 1024 * 2;
    short* w1_pk = (short*)p;   p += (size_t)128 * 1024 * 2;
    short* w2_pk = (short*)p;   p += (size_t)128 * 1024 * 2;
    short* w3_pk = (short*)p;   p += (size_t)128 * 1024 * 2;
    int* count = (int*)p;       p += (size_t)nn * 4;
    int* base = (int*)p;        p += (size_t)(nn + 1) * 4;
    int* cursor = (int*)p;      p += (size_t)nn * 4;
    int* partial = (int*)p;     p += 1024;
    int* slot = (int*)p;        p += (size_t)n_edge * 4;
    // y buffer last; choose dtype by remaining workspace.
    size_t used = (size_t)(p - (char*)d_ws);
    size_t yf_bytes = (size_t)n_edge * EDGE_DIM * 4;
    int use_bf16 = (ws_size < used + yf_bytes) ? 1 : 0;
    float* yf = (float*)p;
    __hip_bfloat16* yb = (__hip_bfloat16*)p;

    const int nblk_scan = (nn + 1023) / 1024;

    hipMemsetAsync(count, 0, (size_t)nn * 4, stream);
    pack_all_kernel<<<104, 256, 0, stream>>>(W_up, W1, W2, W3, wup_pk, w1_pk,
                                             w2_pk, w3_pk);
    count_kernel<<<2048, 256, 0, stream>>>(idx, n_edge, nn, count);
    scan_a<<<nblk_scan, 256, 0, stream>>>(count, base, partial, nn);
    scan_b<<<1, 256, 0, stream>>>(partial, nblk_scan);
    scan_c<<<nblk_scan, 256, 0, stream>>>(base, cursor, partial, nn, n_edge);
    fill_slot_kernel<<<2048, 256, 0, stream>>>(idx, n_edge, nn, cursor, slot);
    scatter_y_kernel<<<4096, 256, 0, stream>>>(x, rbf, slot, W_rbf, yf, yb,
                                               use_bf16, n_edge);
    const int nb = (nn + 63) / 64;
    node_mlp_mfma2<<<nb, 256, 0, stream>>>(yf, yb, use_bf16, base, wup_pk,
                                           w1_pk, w2_pk, w3_pk, b1, b2, b3,
                                           W_out, out, nn);
}

// Round 8
// 425.234 us; speedup vs baseline: 1.2631x; 1.2631x over previous
//
#include <hip/hip_runtime.h>
#include <hip/hip_bf16.h>

#define EDGE_DIM 64
#define UPD 256

typedef __attribute__((ext_vector_type(8))) short bf16x8;
typedef __attribute__((ext_vector_type(4))) float f32x4;

__device__ __forceinline__ short f2bf(float v) {
    __hip_bfloat16 b = __float2bfloat16(v);
    return *(short*)&b;
}
__device__ __forceinline__ float bf2f(short s) {
    __hip_bfloat16 b = *(__hip_bfloat16*)&s;
    return __bfloat162float(b);
}

// ---------------------------------------------------------------------------
// Per-block idx-dtype detection (deterministic across blocks).
// ---------------------------------------------------------------------------
__device__ __forceinline__ int detect_use64_block(const void* idx_v,
                                                  int n_edge, int nn,
                                                  int* bad_s) {
    if (threadIdx.x == 0) *bad_s = 0;
    __syncthreads();
    const long long* p = (const long long*)idx_v;
    int i = threadIdx.x;
    if (i < 256 && i < n_edge) {
        long long v = p[i];
        if (v < 0 || v >= (long long)nn) *bad_s = 1;  // benign race
    }
    __syncthreads();
    return !(*bad_s);
}

// ---------------------------------------------------------------------------
// Counting sort phase A: per-node histogram.
// ---------------------------------------------------------------------------
__global__ __launch_bounds__(256) void count_kernel(
    const void* __restrict__ idx_v, int n_edge, int nn,
    int* __restrict__ count) {
    __shared__ int bad_s;
    const int use64 = detect_use64_block(idx_v, n_edge, nn, &bad_s);
    const long long* i64 = (const long long*)idx_v;
    const int* i32 = (const int*)idx_v;
    for (int e = blockIdx.x * blockDim.x + threadIdx.x; e < n_edge;
         e += gridDim.x * blockDim.x) {
        int n = use64 ? (int)i64[e] : i32[e];
        atomicAdd(&count[n], 1);
    }
}

// ---------------------------------------------------------------------------
// Exclusive scan over count[nn] -> base[nn+1]  (3 kernels).
// ---------------------------------------------------------------------------
__global__ __launch_bounds__(256) void scan_a(const int* __restrict__ count,
                                              int* __restrict__ base,
                                              int* __restrict__ partial,
                                              int nn) {
    __shared__ int s[256];
    const int tid = threadIdx.x;
    const int i0 = blockIdx.x * 1024 + tid * 4;
    int c[4], tsum = 0;
#pragma unroll
    for (int j = 0; j < 4; ++j) {
        c[j] = (i0 + j < nn) ? count[i0 + j] : 0;
        tsum += c[j];
    }
    s[tid] = tsum;
    __syncthreads();
    for (int off = 1; off < 256; off <<= 1) {
        int v = (tid >= off) ? s[tid - off] : 0;
        __syncthreads();
        s[tid] += v;
        __syncthreads();
    }
    int run = s[tid] - tsum;
    if (tid == 255) partial[blockIdx.x] = s[255];
#pragma unroll
    for (int j = 0; j < 4; ++j) {
        if (i0 + j < nn) base[i0 + j] = run;
        run += c[j];
    }
}

__global__ __launch_bounds__(256) void scan_b(int* __restrict__ partial,
                                              int nblk) {
    __shared__ int s[256];
    const int tid = threadIdx.x;
    int v = (tid < nblk) ? partial[tid] : 0;
    s[tid] = v;
    __syncthreads();
    for (int off = 1; off < 256; off <<= 1) {
        int u = (tid >= off) ? s[tid - off] : 0;
        __syncthreads();
        s[tid] += u;
        __syncthreads();
    }
    if (tid < nblk) partial[tid] = s[tid] - v;
}

__global__ __launch_bounds__(256) void scan_c(int* __restrict__ base,
                                              int* __restrict__ cursor,
                                              const int* __restrict__ partial,
                                              int nn, int n_edge) {
    const int tid = threadIdx.x;
    const int b = blockIdx.x;
    const int add = partial[b];
    const int i0 = b * 1024 + tid * 4;
#pragma unroll
    for (int j = 0; j < 4; ++j) {
        int i = i0 + j;
        if (i < nn) {
            int v = base[i] + add;
            base[i] = v;
            cursor[i] = v;
        }
    }
    if (b == 0 && tid == 0) base[nn] = n_edge;
}

// ---------------------------------------------------------------------------
// Phase B: scatter edge ids into node-sorted slot order.
// ---------------------------------------------------------------------------
__global__ __launch_bounds__(256) void fill_order_kernel(
    const void* __restrict__ idx_v, int n_edge, int nn,
    int* __restrict__ cursor, int* __restrict__ order) {
    __shared__ int bad_s;
    const int use64 = detect_use64_block(idx_v, n_edge, nn, &bad_s);
    const long long* i64 = (const long long*)idx_v;
    const int* i32 = (const int*)idx_v;
    for (int e = blockIdx.x * blockDim.x + threadIdx.x; e < n_edge;
         e += gridDim.x * blockDim.x) {
        int n = use64 ? (int)i64[e] : i32[e];
        int p = atomicAdd(&cursor[n], 1);
        order[p] = e;
    }
}

// ---------------------------------------------------------------------------
// Phase C: per-node gather-reduce, 8-edge rounds.
// ALL loads unconditional (tail handled by index clamp + masked accumulate);
// a compiler memory barrier after the 8 order-loads forces them to issue as
// a batch, so the 8 x-row loads + rbf float4 loads are independently in
// flight (~2.3KB/wave/round).
// ---------------------------------------------------------------------------
__global__ __launch_bounds__(256) void gather_kernel(
    const float* __restrict__ x, const float* __restrict__ rbf,
    const int* __restrict__ order, const int* __restrict__ base,
    const float* __restrict__ Wrbf, float* __restrict__ h, int nn) {
    const int lane = threadIdx.x & 63;
    float wreg[16];
#pragma unroll
    for (int q = 0; q < 16; ++q) wreg[q] = Wrbf[q * EDGE_DIM + lane];

    const int wid = __builtin_amdgcn_readfirstlane(threadIdx.x >> 6);
    const int gw = blockIdx.x * 4 + wid;
    const int nwaves = gridDim.x * 4;

    for (int n = gw; n < nn; n += nwaves) {
        const int b0 = base[n], b1 = base[n + 1];
        float acc = 0.f;
        for (int i = b0; i < b1; i += 8) {
            int e[8];
#pragma unroll
            for (int j = 0; j < 8; ++j) {
                int s = i + j;
                s = (s < b1 - 1) ? s : (b1 - 1);  // clamp, no guard
                e[j] = order[s];
            }
            asm volatile("" ::: "memory");  // force the 8 index loads first
            float xv[8];
#pragma unroll
            for (int j = 0; j < 8; ++j)
                xv[j] = x[(size_t)e[j] * EDGE_DIM + lane];
#pragma unroll
            for (int j = 0; j < 8; ++j) {
                const float4* rp = (const float4*)(rbf + (size_t)e[j] * 16);
                float4 r0 = rp[0], r1 = rp[1], r2 = rp[2], r3 = rp[3];
                float g = 0.f;
                g = fmaf(r0.x, wreg[0], g);
                g = fmaf(r0.y, wreg[1], g);
                g = fmaf(r0.z, wreg[2], g);
                g = fmaf(r0.w, wreg[3], g);
                g = fmaf(r1.x, wreg[4], g);
                g = fmaf(r1.y, wreg[5], g);
                g = fmaf(r1.z, wreg[6], g);
                g = fmaf(r1.w, wreg[7], g);
                g = fmaf(r2.x, wreg[8], g);
                g = fmaf(r2.y, wreg[9], g);
                g = fmaf(r2.z, wreg[10], g);
                g = fmaf(r2.w, wreg[11], g);
                g = fmaf(r3.x, wreg[12], g);
                g = fmaf(r3.y, wreg[13], g);
                g = fmaf(r3.z, wreg[14], g);
                g = fmaf(r3.w, wreg[15], g);
                if (i + j < b1) acc = fmaf(g, xv[j], acc);  // uniform mask
            }
        }
        h[(size_t)n * EDGE_DIM + lane] = acc;
    }
}

// ---------------------------------------------------------------------------
// Pack all 4 weight matrices into MFMA-fragment bf16 hi/lo order.
// ---------------------------------------------------------------------------
__device__ __forceinline__ void pack_body(const float* __restrict__ W,
                                          short* __restrict__ out, int t) {
    int l = t & 63, f = t >> 6;
    int kt = f >> 4, nt = f & 15;
    int kbase = kt * 32 + (l >> 4) * 8;
    int col = nt * 16 + (l & 15);
#pragma unroll
    for (int j = 0; j < 8; ++j) {
        float v = W[(kbase + j) * UPD + col];
        short hb = f2bf(v);
        short lb = f2bf(v - bf2f(hb));
        out[f * 1024 + l * 8 + j] = hb;
        out[f * 1024 + 512 + l * 8 + j] = lb;
    }
}

__global__ __launch_bounds__(256) void pack_all_kernel(
    const float* __restrict__ Wup, const float* __restrict__ W1,
    const float* __restrict__ W2, const float* __restrict__ W3,
    short* __restrict__ oup, short* __restrict__ o1, short* __restrict__ o2,
    short* __restrict__ o3) {
    const int b = blockIdx.x;
    if (b < 8) {
        pack_body(Wup, oup, b * 256 + threadIdx.x);
    } else if (b < 40) {
        pack_body(W1, o1, (b - 8) * 256 + threadIdx.x);
    } else if (b < 72) {
        pack_body(W2, o2, (b - 40) * 256 + threadIdx.x);
    } else {
        pack_body(W3, o3, (b - 72) * 256 + threadIdx.x);
    }
}

// ---------------------------------------------------------------------------
// MFMA node MLP: 64-node tile, 8 waves (512 threads), wave wq owns output
// cols [wq*32, wq*32+32). 16 waves/CU occupancy; same per-block weight
// traffic as the 4-wave version.
// ---------------------------------------------------------------------------
template <int NK>
__device__ __forceinline__ void mm_layer(const short* AH, const short* AL,
                                         const short* __restrict__ Wpk,
                                         int lr, int lh, int lane, int wq,
                                         f32x4 acc[4][2]) {
#pragma unroll
    for (int kt = 0; kt < NK; ++kt) {
        bf16x8 a[4][2];
#pragma unroll
        for (int m = 0; m < 4; ++m) {
            int r = m * 16 + lr;
            int ch = (kt * 4 + lh) ^ (r & 7);
            int off = r * 256 + ch * 8;  // shorts
            a[m][0] = *(const bf16x8*)(AH + off);
            a[m][1] = *(const bf16x8*)(AL + off);
        }
        bf16x8 b[2][2];
#pragma unroll
        for (int nf = 0; nf < 2; ++nf) {
            int f = kt * 16 + wq * 2 + nf;
            const short* p = Wpk + f * 1024 + lane * 8;
            b[nf][0] = *(const bf16x8*)(p);
            b[nf][1] = *(const bf16x8*)(p + 512);
        }
        // 3 passes of 8 independent MFMAs
#pragma unroll
        for (int m = 0; m < 4; ++m)
#pragma unroll
            for (int nf = 0; nf < 2; ++nf)
                acc[m][nf] = __builtin_amdgcn_mfma_f32_16x16x32_bf16(
                    a[m][0], b[nf][0], acc[m][nf], 0, 0, 0);
#pragma unroll
        for (int m = 0; m < 4; ++m)
#pragma unroll
            for (int nf = 0; nf < 2; ++nf)
                acc[m][nf] = __builtin_amdgcn_mfma_f32_16x16x32_bf16(
                    a[m][0], b[nf][1], acc[m][nf], 0, 0, 0);
#pragma unroll
        for (int m = 0; m < 4; ++m)
#pragma unroll
            for (int nf = 0; nf < 2; ++nf)
                acc[m][nf] = __builtin_amdgcn_mfma_f32_16x16x32_bf16(
                    a[m][1], b[nf][0], acc[m][nf], 0, 0, 0);
    }
}

template <bool ACT>
__device__ __forceinline__ void epilogue_store(f32x4 acc[4][2], short* AH,
                                               short* AL,
                                               const float* __restrict__ bias,
                                               int lr, int lh, int wq) {
    float bv[2] = {0.f, 0.f};
    if (bias) {
#pragma unroll
        for (int nf = 0; nf < 2; ++nf) bv[nf] = bias[wq * 32 + nf * 16 + lr];
    }
#pragma unroll
    for (int m = 0; m < 4; ++m)
#pragma unroll
        for (int nf = 0; nf < 2; ++nf) {
            int c = wq * 32 + nf * 16 + lr;
#pragma unroll
            for (int reg = 0; reg < 4; ++reg) {
                float v = acc[m][nf][reg] + bv[nf];
                if (ACT) v = v / (1.f + __expf(-v));
                int r = m * 16 + lh * 4 + reg;
                short hb = f2bf(v);
                short lb = f2bf(v - bf2f(hb));
                int off = r * 256 + (((c >> 3) ^ (r & 7)) * 8) + (c & 7);
                AH[off] = hb;
                AL[off] = lb;
            }
        }
}

__global__ __launch_bounds__(512, 2) void node_mlp_mfma(
    const float* __restrict__ h,
    const short* __restrict__ Wup_pk, const short* __restrict__ W1_pk,
    const short* __restrict__ W2_pk, const short* __restrict__ W3_pk,
    const float* __restrict__ b1, const float* __restrict__ b2,
    const float* __restrict__ b3, const float* __restrict__ W_out,
    float* __restrict__ out, int nn) {
    __shared__ short AH[64 * 256];
    __shared__ short AL[64 * 256];
    __shared__ float Bpart[64 * 8];

    const int tid = threadIdx.x;
    const int lane = tid & 63;
    const int wq = __builtin_amdgcn_readfirstlane(tid >> 6);  // 0..7
    const int lr = lane & 15, lh = lane >> 4;
    const int node0 = blockIdx.x * 64;

    // Stage h tile (64 x 64 f32) -> hi/lo bf16, swizzled. 1024 float4 / 512.
#pragma unroll
    for (int i = 0; i < 2; ++i) {
        int idx4 = tid + i * 512;
        int r = idx4 >> 4, c4 = idx4 & 15;
        float4 v = {0.f, 0.f, 0.f, 0.f};
        if (node0 + r < nn)
            v = *(const float4*)(h + (size_t)(node0 + r) * EDGE_DIM + c4 * 4);
        short h0 = f2bf(v.x), h1 = f2bf(v.y), h2 = f2bf(v.z), h3 = f2bf(v.w);
        short l0 = f2bf(v.x - bf2f(h0)), l1 = f2bf(v.y - bf2f(h1));
        short l2 = f2bf(v.z - bf2f(h2)), l3 = f2bf(v.w - bf2f(h3));
        int off = r * 256 + (((c4 >> 1) ^ (r & 7)) * 8) + (c4 & 1) * 4;
        uint2 hw, lw;
        hw.x = (unsigned short)h0 | ((unsigned)(unsigned short)h1 << 16);
        hw.y = (unsigned short)h2 | ((unsigned)(unsigned short)h3 << 16);
        lw.x = (unsigned short)l0 | ((unsigned)(unsigned short)l1 << 16);
        lw.y = (unsigned short)l2 | ((unsigned)(unsigned short)l3 << 16);
        *(uint2*)(AH + off) = hw;
        *(uint2*)(AL + off) = lw;
    }
    __syncthreads();

    f32x4 acc[4][2];

#pragma unroll
    for (int m = 0; m < 4; ++m)
#pragma unroll
        for (int n = 0; n < 2; ++n) acc[m][n] = (f32x4){0.f, 0.f, 0.f, 0.f};
    mm_layer<2>(AH, AL, Wup_pk, lr, lh, lane, wq, acc);
    __syncthreads();
    epilogue_store<false>(acc, AH, AL, nullptr, lr, lh, wq);
    __syncthreads();

#pragma unroll
    for (int m = 0; m < 4; ++m)
#pragma unroll
        for (int n = 0; n < 2; ++n) acc[m][n] = (f32x4){0.f, 0.f, 0.f, 0.f};
    mm_layer<8>(AH, AL, W1_pk, lr, lh, lane, wq, acc);
    __syncthreads();
    epilogue_store<true>(acc, AH, AL, b1, lr, lh, wq);
    __syncthreads();

#pragma unroll
    for (int m = 0; m < 4; ++m)
#pragma unroll
        for (int n = 0; n < 2; ++n) acc[m][n] = (f32x4){0.f, 0.f, 0.f, 0.f};
    mm_layer<8>(AH, AL, W2_pk, lr, lh, lane, wq, acc);
    __syncthreads();
    epilogue_store<true>(acc, AH, AL, b2, lr, lh, wq);
    __syncthreads();

#pragma unroll
    for (int m = 0; m < 4; ++m)
#pragma unroll
        for (int n = 0; n < 2; ++n) acc[m][n] = (f32x4){0.f, 0.f, 0.f, 0.f};
    mm_layer<8>(AH, AL, W3_pk, lr, lh, lane, wq, acc);

    float b3v[2], wo[2];
#pragma unroll
    for (int nf = 0; nf < 2; ++nf) {
        int c = wq * 32 + nf * 16 + lr;
        b3v[nf] = b3[c];
        wo[nf] = W_out[c];
    }
#pragma unroll
    for (int m = 0; m < 4; ++m) {
#pragma unroll
        for (int reg = 0; reg < 4; ++reg) {
            float s = 0.f;
#pragma unroll
            for (int nf = 0; nf < 2; ++nf) {
                float v = acc[m][nf][reg] + b3v[nf];
                v = v / (1.f + __expf(-v));
                s = fmaf(v, wo[nf], s);
            }
            s += __shfl_xor(s, 1);
            s += __shfl_xor(s, 2);
            s += __shfl_xor(s, 4);
            s += __shfl_xor(s, 8);
            if (lr == 0) Bpart[(m * 16 + lh * 4 + reg) * 8 + wq] = s;
        }
    }
    __syncthreads();
    if (tid < 64) {
        float s = 0.f;
#pragma unroll
        for (int w = 0; w < 8; ++w) s += Bpart[tid * 8 + w];
        if (node0 + tid < nn) out[node0 + tid] = s;
    }
}

// ---------------------------------------------------------------------------
extern "C" void kernel_launch(void* const* d_in, const int* in_sizes, int n_in,
                              void* d_out, int out_size, void* d_ws, size_t ws_size,
                              hipStream_t stream) {
    const float* x     = (const float*)d_in[0];
    const float* rbf   = (const float*)d_in[1];
    const void*  idx   = d_in[2];
    const float* W_rbf = (const float*)d_in[4];
    const float* W_up  = (const float*)d_in[5];
    const float* W1    = (const float*)d_in[6];
    const float* b1    = (const float*)d_in[7];
    const float* W2    = (const float*)d_in[8];
    const float* b2    = (const float*)d_in[9];
    const float* W3    = (const float*)d_in[10];
    const float* b3    = (const float*)d_in[11];
    const float* W_out = (const float*)d_in[12];
    float* out = (float*)d_out;

    const int n_edge = in_sizes[0] / EDGE_DIM;
    const int nn = out_size;

    // Workspace layout
    char* p = (char*)d_ws;
    float* h = (float*)p;            p += (size_t)nn * EDGE_DIM * sizeof(float);
    short* wup_pk = (short*)p;       p += 32 * 1024 * sizeof(short);
    short* w1_pk = (short*)p;        p += 128 * 1024 * sizeof(short);
    short* w2_pk = (short*)p;        p += 128 * 1024 * sizeof(short);
    short* w3_pk = (short*)p;        p += 128 * 1024 * sizeof(short);
    int* count = (int*)p;            p += (size_t)nn * sizeof(int);
    int* base = (int*)p;             p += (size_t)(nn + 1) * sizeof(int);
    int* cursor = (int*)p;           p += (size_t)nn * sizeof(int);
    int* partial = (int*)p;          p += 1024;
    int* order = (int*)p;

    const int nblk_scan = (nn + 1023) / 1024;

    hipMemsetAsync(count, 0, (size_t)nn * sizeof(int), stream);
    pack_all_kernel<<<104, 256, 0, stream>>>(W_up, W1, W2, W3, wup_pk, w1_pk,
                                             w2_pk, w3_pk);
    count_kernel<<<2048, 256, 0, stream>>>(idx, n_edge, nn, count);
    scan_a<<<nblk_scan, 256, 0, stream>>>(count, base, partial, nn);
    scan_b<<<1, 256, 0, stream>>>(partial, nblk_scan);
    scan_c<<<nblk_scan, 256, 0, stream>>>(base, cursor, partial, nn, n_edge);
    fill_order_kernel<<<2048, 256, 0, stream>>>(idx, n_edge, nn, cursor,
                                                order);
    gather_kernel<<<4096, 256, 0, stream>>>(x, rbf, order, base, W_rbf, h, nn);

    const int nb = (nn + 63) / 64;
    node_mlp_mfma<<<nb, 512, 0, stream>>>(h, wup_pk, w1_pk, w2_pk, w3_pk,
                                          b1, b2, b3, W_out, out, nn);
}

// Round 9
// 399.749 us; speedup vs baseline: 1.3436x; 1.0638x over previous
//
#include <hip/hip_runtime.h>
#include <hip/hip_bf16.h>

#define EDGE_DIM 64
#define UPD 256

typedef __attribute__((ext_vector_type(8))) short bf16x8;
typedef __attribute__((ext_vector_type(4))) float f32x4;

__device__ __forceinline__ short f2bf(float v) {
    __hip_bfloat16 b = __float2bfloat16(v);
    return *(short*)&b;
}
__device__ __forceinline__ float bf2f(short s) {
    __hip_bfloat16 b = *(__hip_bfloat16*)&s;
    return __bfloat162float(b);
}

// ---------------------------------------------------------------------------
// Per-block idx-dtype detection (deterministic across blocks).
// ---------------------------------------------------------------------------
__device__ __forceinline__ int detect_use64_block(const void* idx_v,
                                                  int n_edge, int nn,
                                                  int* bad_s) {
    if (threadIdx.x == 0) *bad_s = 0;
    __syncthreads();
    const long long* p = (const long long*)idx_v;
    int i = threadIdx.x;
    if (i < 256 && i < n_edge) {
        long long v = p[i];
        if (v < 0 || v >= (long long)nn) *bad_s = 1;  // benign race
    }
    __syncthreads();
    return !(*bad_s);
}

// ---------------------------------------------------------------------------
// Counting sort phase A: per-node histogram.
// ---------------------------------------------------------------------------
__global__ __launch_bounds__(256) void count_kernel(
    const void* __restrict__ idx_v, int n_edge, int nn,
    int* __restrict__ count) {
    __shared__ int bad_s;
    const int use64 = detect_use64_block(idx_v, n_edge, nn, &bad_s);
    const long long* i64 = (const long long*)idx_v;
    const int* i32 = (const int*)idx_v;
    for (int e = blockIdx.x * blockDim.x + threadIdx.x; e < n_edge;
         e += gridDim.x * blockDim.x) {
        int n = use64 ? (int)i64[e] : i32[e];
        atomicAdd(&count[n], 1);
    }
}

// ---------------------------------------------------------------------------
// Exclusive scan over count[nn] -> base[nn+1]  (3 kernels).
// ---------------------------------------------------------------------------
__global__ __launch_bounds__(256) void scan_a(const int* __restrict__ count,
                                              int* __restrict__ base,
                                              int* __restrict__ partial,
                                              int nn) {
    __shared__ int s[256];
    const int tid = threadIdx.x;
    const int i0 = blockIdx.x * 1024 + tid * 4;
    int c[4], tsum = 0;
#pragma unroll
    for (int j = 0; j < 4; ++j) {
        c[j] = (i0 + j < nn) ? count[i0 + j] : 0;
        tsum += c[j];
    }
    s[tid] = tsum;
    __syncthreads();
    for (int off = 1; off < 256; off <<= 1) {
        int v = (tid >= off) ? s[tid - off] : 0;
        __syncthreads();
        s[tid] += v;
        __syncthreads();
    }
    int run = s[tid] - tsum;
    if (tid == 255) partial[blockIdx.x] = s[255];
#pragma unroll
    for (int j = 0; j < 4; ++j) {
        if (i0 + j < nn) base[i0 + j] = run;
        run += c[j];
    }
}

__global__ __launch_bounds__(256) void scan_b(int* __restrict__ partial,
                                              int nblk) {
    __shared__ int s[256];
    const int tid = threadIdx.x;
    int v = (tid < nblk) ? partial[tid] : 0;
    s[tid] = v;
    __syncthreads();
    for (int off = 1; off < 256; off <<= 1) {
        int u = (tid >= off) ? s[tid - off] : 0;
        __syncthreads();
        s[tid] += u;
        __syncthreads();
    }
    if (tid < nblk) partial[tid] = s[tid] - v;
}

__global__ __launch_bounds__(256) void scan_c(int* __restrict__ base,
                                              int* __restrict__ cursor,
                                              const int* __restrict__ partial,
                                              int nn, int n_edge) {
    const int tid = threadIdx.x;
    const int b = blockIdx.x;
    const int add = partial[b];
    const int i0 = b * 1024 + tid * 4;
#pragma unroll
    for (int j = 0; j < 4; ++j) {
        int i = i0 + j;
        if (i < nn) {
            int v = base[i] + add;
            base[i] = v;
            cursor[i] = v;
        }
    }
    if (b == 0 && tid == 0) base[nn] = n_edge;
}

// ---------------------------------------------------------------------------
// Phase B: scatter edge ids + node ids into node-sorted slot order.
// ---------------------------------------------------------------------------
__global__ __launch_bounds__(256) void fill_order_kernel(
    const void* __restrict__ idx_v, int n_edge, int nn,
    int* __restrict__ cursor, int* __restrict__ order,
    int* __restrict__ nodeof) {
    __shared__ int bad_s;
    const int use64 = detect_use64_block(idx_v, n_edge, nn, &bad_s);
    const long long* i64 = (const long long*)idx_v;
    const int* i32 = (const int*)idx_v;
    for (int e = blockIdx.x * blockDim.x + threadIdx.x; e < n_edge;
         e += gridDim.x * blockDim.x) {
        int n = use64 ? (int)i64[e] : i32[e];
        int p = atomicAdd(&cursor[n], 1);
        order[p] = e;
        nodeof[p] = n;
    }
}

// ---------------------------------------------------------------------------
// Phase C: slot-chunked segmented sum. Wave owns 16 CONSECUTIVE slots of the
// node-sorted edge list. s0 is wave-uniform, so order/nodeof/rbf loads are
// uniform-address (s_load, SGPR results); the 16 x-row loads are independent
// vector loads (SGPR base + lane*4). No guards in the hot path, 16-deep
// memory ILP, one atomicAdd burst per node-segment.
// ---------------------------------------------------------------------------
__global__ __launch_bounds__(256) void segsum_kernel(
    const float* __restrict__ x, const float* __restrict__ rbf,
    const int* __restrict__ order, const int* __restrict__ nodeof,
    const float* __restrict__ Wrbf, float* __restrict__ h, int n_edge) {
    const int lane = threadIdx.x & 63;
    float wreg[16];
#pragma unroll
    for (int q = 0; q < 16; ++q) wreg[q] = Wrbf[q * EDGE_DIM + lane];

    const int wid = __builtin_amdgcn_readfirstlane(threadIdx.x >> 6);
    const int nchunks = n_edge >> 4;  // full 16-slot chunks
    const int stride = gridDim.x * 4;

    for (int c = blockIdx.x * 4 + wid; c < nchunks; c += stride) {
        const int s0 = c * 16;  // wave-uniform
        int e[16], nd[16];
#pragma unroll
        for (int j = 0; j < 16; ++j) e[j] = order[s0 + j];
#pragma unroll
        for (int j = 0; j < 16; ++j) nd[j] = nodeof[s0 + j];
        asm volatile("" ::: "memory");
        float xv[16];
#pragma unroll
        for (int j = 0; j < 16; ++j)
            xv[j] = x[(size_t)e[j] * EDGE_DIM + lane];
        float g[16];
#pragma unroll
        for (int j = 0; j < 16; ++j) {
            const float* rp = rbf + (size_t)e[j] * 16;  // uniform address
            float s = 0.f;
#pragma unroll
            for (int q = 0; q < 16; ++q) s = fmaf(rp[q], wreg[q], s);
            g[j] = s;
        }
        float acc = g[0] * xv[0];
        int cur = nd[0];
#pragma unroll
        for (int j = 1; j < 16; ++j) {
            if (nd[j] != cur) {  // wave-uniform branch
                atomicAdd(&h[(size_t)cur * EDGE_DIM + lane], acc);
                cur = nd[j];
                acc = 0.f;
            }
            acc = fmaf(g[j], xv[j], acc);
        }
        atomicAdd(&h[(size_t)cur * EDGE_DIM + lane], acc);
    }

    // Tail slots (< 16), handled once by the first wave of block 0.
    if (blockIdx.x == 0 && wid == 0) {
        float acc = 0.f;
        int cur = -1;
        for (int s = nchunks * 16; s < n_edge; ++s) {
            int e = order[s];
            int nd = nodeof[s];
            float xv = x[(size_t)e * EDGE_DIM + lane];
            const float* rp = rbf + (size_t)e * 16;
            float gg = 0.f;
#pragma unroll
            for (int q = 0; q < 16; ++q) gg = fmaf(rp[q], wreg[q], gg);
            if (nd != cur) {
                if (cur >= 0)
                    atomicAdd(&h[(size_t)cur * EDGE_DIM + lane], acc);
                cur = nd;
                acc = 0.f;
            }
            acc = fmaf(gg, xv, acc);
        }
        if (cur >= 0) atomicAdd(&h[(size_t)cur * EDGE_DIM + lane], acc);
    }
}

// ---------------------------------------------------------------------------
// Pack all 4 weight matrices into MFMA-fragment bf16 hi/lo order.
// ---------------------------------------------------------------------------
__device__ __forceinline__ void pack_body(const float* __restrict__ W,
                                          short* __restrict__ out, int t) {
    int l = t & 63, f = t >> 6;
    int kt = f >> 4, nt = f & 15;
    int kbase = kt * 32 + (l >> 4) * 8;
    int col = nt * 16 + (l & 15);
#pragma unroll
    for (int j = 0; j < 8; ++j) {
        float v = W[(kbase + j) * UPD + col];
        short hb = f2bf(v);
        short lb = f2bf(v - bf2f(hb));
        out[f * 1024 + l * 8 + j] = hb;
        out[f * 1024 + 512 + l * 8 + j] = lb;
    }
}

__global__ __launch_bounds__(256) void pack_all_kernel(
    const float* __restrict__ Wup, const float* __restrict__ W1,
    const float* __restrict__ W2, const float* __restrict__ W3,
    short* __restrict__ oup, short* __restrict__ o1, short* __restrict__ o2,
    short* __restrict__ o3) {
    const int b = blockIdx.x;
    if (b < 8) {
        pack_body(Wup, oup, b * 256 + threadIdx.x);
    } else if (b < 40) {
        pack_body(W1, o1, (b - 8) * 256 + threadIdx.x);
    } else if (b < 72) {
        pack_body(W2, o2, (b - 40) * 256 + threadIdx.x);
    } else {
        pack_body(W3, o3, (b - 72) * 256 + threadIdx.x);
    }
}

// ---------------------------------------------------------------------------
// MFMA node MLP (R4 geometry: 64-node tile, 4 waves, wave owns 64 cols).
// ---------------------------------------------------------------------------
template <int NK>
__device__ __forceinline__ void mm_layer(const short* AH, const short* AL,
                                         const short* __restrict__ Wpk,
                                         int lr, int lh, int lane, int wq,
                                         f32x4 acc[4][4]) {
#pragma unroll
    for (int kt = 0; kt < NK; ++kt) {
        bf16x8 a[4][2];
#pragma unroll
        for (int m = 0; m < 4; ++m) {
            int r = m * 16 + lr;
            int ch = (kt * 4 + lh) ^ (r & 7);
            int off = r * 256 + ch * 8;  // shorts
            a[m][0] = *(const bf16x8*)(AH + off);
            a[m][1] = *(const bf16x8*)(AL + off);
        }
        bf16x8 b[4][2];
#pragma unroll
        for (int nf = 0; nf < 4; ++nf) {
            int f = kt * 16 + wq * 4 + nf;
            const short* p = Wpk + f * 1024 + lane * 8;
            b[nf][0] = *(const bf16x8*)(p);
            b[nf][1] = *(const bf16x8*)(p + 512);
        }
#pragma unroll
        for (int m = 0; m < 4; ++m)
#pragma unroll
            for (int nf = 0; nf < 4; ++nf)
                acc[m][nf] = __builtin_amdgcn_mfma_f32_16x16x32_bf16(
                    a[m][0], b[nf][0], acc[m][nf], 0, 0, 0);
#pragma unroll
        for (int m = 0; m < 4; ++m)
#pragma unroll
            for (int nf = 0; nf < 4; ++nf)
                acc[m][nf] = __builtin_amdgcn_mfma_f32_16x16x32_bf16(
                    a[m][0], b[nf][1], acc[m][nf], 0, 0, 0);
#pragma unroll
        for (int m = 0; m < 4; ++m)
#pragma unroll
            for (int nf = 0; nf < 4; ++nf)
                acc[m][nf] = __builtin_amdgcn_mfma_f32_16x16x32_bf16(
                    a[m][1], b[nf][0], acc[m][nf], 0, 0, 0);
    }
}

template <bool ACT>
__device__ __forceinline__ void epilogue_store(f32x4 acc[4][4], short* AH,
                                               short* AL,
                                               const float* __restrict__ bias,
                                               int lr, int lh, int wq) {
    float bv[4] = {0.f, 0.f, 0.f, 0.f};
    if (bias) {
#pragma unroll
        for (int nf = 0; nf < 4; ++nf) bv[nf] = bias[wq * 64 + nf * 16 + lr];
    }
#pragma unroll
    for (int m = 0; m < 4; ++m)
#pragma unroll
        for (int nf = 0; nf < 4; ++nf) {
            int c = wq * 64 + nf * 16 + lr;
#pragma unroll
            for (int reg = 0; reg < 4; ++reg) {
                float v = acc[m][nf][reg] + bv[nf];
                if (ACT) v = v / (1.f + __expf(-v));
                int r = m * 16 + lh * 4 + reg;
                short hb = f2bf(v);
                short lb = f2bf(v - bf2f(hb));
                int off = r * 256 + (((c >> 3) ^ (r & 7)) * 8) + (c & 7);
                AH[off] = hb;
                AL[off] = lb;
            }
        }
}

__global__ __launch_bounds__(256, 2) void node_mlp_mfma(
    const float* __restrict__ h,
    const short* __restrict__ Wup_pk, const short* __restrict__ W1_pk,
    const short* __restrict__ W2_pk, const short* __restrict__ W3_pk,
    const float* __restrict__ b1, const float* __restrict__ b2,
    const float* __restrict__ b3, const float* __restrict__ W_out,
    float* __restrict__ out, int nn) {
    __shared__ short AH[64 * 256];
    __shared__ short AL[64 * 256];
    __shared__ float Bpart[64 * 4];

    const int tid = threadIdx.x;
    const int lane = tid & 63, wq = tid >> 6;
    const int lr = lane & 15, lh = lane >> 4;
    const int node0 = blockIdx.x * 64;

#pragma unroll
    for (int i = 0; i < 4; ++i) {
        int idx4 = tid + i * 256;
        int r = idx4 >> 4, c4 = idx4 & 15;
        float4 v = {0.f, 0.f, 0.f, 0.f};
        if (node0 + r < nn)
            v = *(const float4*)(h + (size_t)(node0 + r) * EDGE_DIM + c4 * 4);
        short h0 = f2bf(v.x), h1 = f2bf(v.y), h2 = f2bf(v.z), h3 = f2bf(v.w);
        short l0 = f2bf(v.x - bf2f(h0)), l1 = f2bf(v.y - bf2f(h1));
        short l2 = f2bf(v.z - bf2f(h2)), l3 = f2bf(v.w - bf2f(h3));
        int off = r * 256 + (((c4 >> 1) ^ (r & 7)) * 8) + (c4 & 1) * 4;
        uint2 hw, lw;
        hw.x = (unsigned short)h0 | ((unsigned)(unsigned short)h1 << 16);
        hw.y = (unsigned short)h2 | ((unsigned)(unsigned short)h3 << 16);
        lw.x = (unsigned short)l0 | ((unsigned)(unsigned short)l1 << 16);
        lw.y = (unsigned short)l2 | ((unsigned)(unsigned short)l3 << 16);
        *(uint2*)(AH + off) = hw;
        *(uint2*)(AL + off) = lw;
    }
    __syncthreads();

    f32x4 acc[4][4];

#pragma unroll
    for (int m = 0; m < 4; ++m)
#pragma unroll
        for (int n = 0; n < 4; ++n) acc[m][n] = (f32x4){0.f, 0.f, 0.f, 0.f};
    mm_layer<2>(AH, AL, Wup_pk, lr, lh, lane, wq, acc);
    __syncthreads();
    epilogue_store<false>(acc, AH, AL, nullptr, lr, lh, wq);
    __syncthreads();

#pragma unroll
    for (int m = 0; m < 4; ++m)
#pragma unroll
        for (int n = 0; n < 4; ++n) acc[m][n] = (f32x4){0.f, 0.f, 0.f, 0.f};
    mm_layer<8>(AH, AL, W1_pk, lr, lh, lane, wq, acc);
    __syncthreads();
    epilogue_store<true>(acc, AH, AL, b1, lr, lh, wq);
    __syncthreads();

#pragma unroll
    for (int m = 0; m < 4; ++m)
#pragma unroll
        for (int n = 0; n < 4; ++n) acc[m][n] = (f32x4){0.f, 0.f, 0.f, 0.f};
    mm_layer<8>(AH, AL, W2_pk, lr, lh, lane, wq, acc);
    __syncthreads();
    epilogue_store<true>(acc, AH, AL, b2, lr, lh, wq);
    __syncthreads();

#pragma unroll
    for (int m = 0; m < 4; ++m)
#pragma unroll
        for (int n = 0; n < 4; ++n) acc[m][n] = (f32x4){0.f, 0.f, 0.f, 0.f};
    mm_layer<8>(AH, AL, W3_pk, lr, lh, lane, wq, acc);

    float b3v[4], wo[4];
#pragma unroll
    for (int nf = 0; nf < 4; ++nf) {
        int c = wq * 64 + nf * 16 + lr;
        b3v[nf] = b3[c];
        wo[nf] = W_out[c];
    }
#pragma unroll
    for (int m = 0; m < 4; ++m) {
#pragma unroll
        for (int reg = 0; reg < 4; ++reg) {
            float s = 0.f;
#pragma unroll
            for (int nf = 0; nf < 4; ++nf) {
                float v = acc[m][nf][reg] + b3v[nf];
                v = v / (1.f + __expf(-v));
                s = fmaf(v, wo[nf], s);
            }
            s += __shfl_xor(s, 1);
            s += __shfl_xor(s, 2);
            s += __shfl_xor(s, 4);
            s += __shfl_xor(s, 8);
            if (lr == 0) Bpart[(m * 16 + lh * 4 + reg) * 4 + wq] = s;
        }
    }
    __syncthreads();
    if (tid < 64) {
        float s = Bpart[tid * 4] + Bpart[tid * 4 + 1] + Bpart[tid * 4 + 2] +
                  Bpart[tid * 4 + 3];
        if (node0 + tid < nn) out[node0 + tid] = s;
    }
}

// ---------------------------------------------------------------------------
extern "C" void kernel_launch(void* const* d_in, const int* in_sizes, int n_in,
                              void* d_out, int out_size, void* d_ws, size_t ws_size,
                              hipStream_t stream) {
    const float* x     = (const float*)d_in[0];
    const float* rbf   = (const float*)d_in[1];
    const void*  idx   = d_in[2];
    const float* W_rbf = (const float*)d_in[4];
    const float* W_up  = (const float*)d_in[5];
    const float* W1    = (const float*)d_in[6];
    const float* b1    = (const float*)d_in[7];
    const float* W2    = (const float*)d_in[8];
    const float* b2    = (const float*)d_in[9];
    const float* W3    = (const float*)d_in[10];
    const float* b3    = (const float*)d_in[11];
    const float* W_out = (const float*)d_in[12];
    float* out = (float*)d_out;

    const int n_edge = in_sizes[0] / EDGE_DIM;
    const int nn = out_size;

    // Workspace layout
    char* p = (char*)d_ws;
    float* h = (float*)p;            p += (size_t)nn * EDGE_DIM * sizeof(float);
    short* wup_pk = (short*)p;       p += 32 * 1024 * sizeof(short);
    short* w1_pk = (short*)p;        p += 128 * 1024 * sizeof(short);
    short* w2_pk = (short*)p;        p += 128 * 1024 * sizeof(short);
    short* w3_pk = (short*)p;        p += 128 * 1024 * sizeof(short);
    int* count = (int*)p;            p += (size_t)nn * sizeof(int);
    int* base = (int*)p;             p += (size_t)(nn + 1) * sizeof(int);
    int* cursor = (int*)p;           p += (size_t)nn * sizeof(int);
    int* partial = (int*)p;          p += 1024;
    int* order = (int*)p;            p += (size_t)n_edge * sizeof(int);
    int* nodeof = (int*)p;

    const int nblk_scan = (nn + 1023) / 1024;

    hipMemsetAsync(h, 0, (size_t)nn * EDGE_DIM * sizeof(float), stream);
    hipMemsetAsync(count, 0, (size_t)nn * sizeof(int), stream);
    pack_all_kernel<<<104, 256, 0, stream>>>(W_up, W1, W2, W3, wup_pk, w1_pk,
                                             w2_pk, w3_pk);
    count_kernel<<<2048, 256, 0, stream>>>(idx, n_edge, nn, count);
    scan_a<<<nblk_scan, 256, 0, stream>>>(count, base, partial, nn);
    scan_b<<<1, 256, 0, stream>>>(partial, nblk_scan);
    scan_c<<<nblk_scan, 256, 0, stream>>>(base, cursor, partial, nn, n_edge);
    fill_order_kernel<<<2048, 256, 0, stream>>>(idx, n_edge, nn, cursor,
                                                order, nodeof);
    segsum_kernel<<<4096, 256, 0, stream>>>(x, rbf, order, nodeof, W_rbf, h,
                                            n_edge);
    const int nb = (nn + 63) / 64;
    node_mlp_mfma<<<nb, 256, 0, stream>>>(h, wup_pk, w1_pk, w2_pk, w3_pk,
                                          b1, b2, b3, W_out, out, nn);
}